// Round 2
// baseline (1173.277 us; speedup 1.0000x reference)
//
#include <hip/hip_runtime.h>
#include <math.h>

constexpr int N_SEQ  = 4096;
constexpr int BSZ    = 4;
constexpr int CIN    = 384;
constexpr int CDSSP  = 64;
constexpr int CHID   = 128;
constexpr int NBLK   = 4;
constexpr int NTOK   = BSZ * N_SEQ;        // 16384 tokens
constexpr int TPB    = 64;                 // tokens per MLP block (= lanes per wave)
constexpr int MLP_BLOCKS  = NTOK / TPB;    // 256  (1 per CU)
constexpr int ZERO_BLOCKS = 2048;
constexpr size_t OUT_ELEMS = (size_t)BSZ * N_SEQ * N_SEQ;  // 67108864
constexpr int LDAP = 65;                   // padded row stride of act LDS (bank-rotate)

__device__ __forceinline__ float softplus_f(float x) {
    return fmaxf(x, 0.f) + log1pf(expf(-fabsf(x)));   // stable softplus
}

// Fused kernel:
//  blocks [0, MLP_BLOCKS): batched MLP. lane = token, wave w owns channels [32w,32w+32).
//    Weights are read at wave-uniform addresses -> scalar loads (K$ pipe), activations
//    live in VGPRs / tiny LDS exchange. GEMM uses NO LDS bandwidth for weights.
//  blocks [MLP_BLOCKS, ...): zero-fill d_out (HBM-write-bound) -- co-executes on the
//    store pipe while MLP blocks burn VALU.
__global__ __launch_bounds__(256) void mlp_zero_kernel(
    const float* __restrict__ s, const float* __restrict__ s_init,
    const float* __restrict__ dssp,
    const float* __restrict__ W_in,   const float* __restrict__ b_in,
    const float* __restrict__ W_init, const float* __restrict__ b_init,
    const float* __restrict__ W_dssp, const float* __restrict__ b_dssp,
    const float* __restrict__ W1,     const float* __restrict__ b1,
    const float* __restrict__ W2,     const float* __restrict__ b2,
    const float* __restrict__ W_out,  const float* __restrict__ b_out,
    const float* __restrict__ W_mult, const float* __restrict__ b_mult,
    float* __restrict__ ws, float* __restrict__ out)
{
    // Activation exchange buffer: A2[k][t], k-major, token-inner, pad-65.
    // GEMM read  A2[k*65+lane]  : bank (k+lane)%32 -> 2-way (free).
    // Stage write A2[k*65+t]    : lanes vary k     -> 2-way (free).
    __shared__ float A2[CHID * LDAP];   // 33.3 KB

    if (blockIdx.x >= MLP_BLOCKS) {
        const int zb = (int)blockIdx.x - MLP_BLOCKS;
        const size_t chunk = OUT_ELEMS / ZERO_BLOCKS;          // 32768 floats
        float4* dst = (float4*)(out + (size_t)zb * chunk);
        const float4 z = make_float4(0.f, 0.f, 0.f, 0.f);
        for (int i = threadIdx.x; i < (int)(chunk / 4); i += 256) dst[i] = z;
        return;
    }

    const int tid  = (int)threadIdx.x;
    const int lane = tid & 63;                 // token within block
    const int wv   = tid >> 6;                 // wave id 0..3
    const int jb   = __builtin_amdgcn_readfirstlane(wv * 32);  // channel base, forced uniform
    const int t0   = (int)blockIdx.x * TPB;
    const int g    = t0 + lane;                // global token

    // ---- stage relu(src[t0..t0+63][k0..k0+kn)) -> A2[k][t], coalesced global reads ----
    auto stage = [&](const float* __restrict__ src, int C, int k0, int kn, int kshift) {
        const int tot = kn * TPB;
        for (int idx = tid; idx < tot; idx += 256) {
            const int t = idx >> kshift;
            const int k = idx & (kn - 1);
            const float v = src[(size_t)(t0 + t) * C + k0 + k];
            A2[k * LDAP + t] = fmaxf(v, 0.f);
        }
    };

    // ---- acc[j] += sum_k W[jb+j][k0+k] * A2[k][lane], weights wave-uniform (scalar) ----
    auto gemm_chunk = [&](float (&acc)[32], const float* __restrict__ Wbase, int K, int k0, int kn) {
        for (int r = 0; r < kn; r += 8) {
            float a[8];
            #pragma unroll
            for (int i = 0; i < 8; ++i) a[i] = A2[(r + i) * LDAP + lane];
            #pragma unroll
            for (int j = 0; j < 32; ++j) {
                const float* __restrict__ wr = Wbase + (size_t)(jb + j) * K + (k0 + r);
                #pragma unroll
                for (int i = 0; i < 8; ++i) acc[j] = fmaf(wr[i], a[i], acc[j]);
            }
        }
    };

    // ---- input layer ----
    float hacc[32];
    #pragma unroll
    for (int j = 0; j < 32; ++j)
        hacc[j] = b_in[jb + j] + b_init[jb + j] + b_dssp[jb + j];

    #pragma unroll 1
    for (int sidx = 0; sidx < 2; ++sidx) {
        const float* src = sidx ? s_init : s;
        const float* W   = sidx ? W_init : W_in;
        #pragma unroll 1
        for (int c = 0; c < 3; ++c) {
            __syncthreads();
            stage(src, CIN, c * 128, 128, 7);
            __syncthreads();
            gemm_chunk(hacc, W, CIN, c * 128, 128);
        }
    }
    __syncthreads();
    stage(dssp, CDSSP, 0, 64, 6);
    __syncthreads();
    gemm_chunk(hacc, W_dssp, CDSSP, 0, 64);

    // ---- resnet blocks: h += W2 relu(W1 relu(h) + b1) + b2 ----
    #pragma unroll 1
    for (int rb = 0; rb < NBLK; ++rb) {
        __syncthreads();                        // prior A2 readers done
        #pragma unroll
        for (int j = 0; j < 32; ++j)
            A2[(jb + j) * LDAP + lane] = fmaxf(hacc[j], 0.f);
        __syncthreads();

        float vacc[32];
        #pragma unroll
        for (int j = 0; j < 32; ++j) vacc[j] = b1[rb * CHID + jb + j];
        gemm_chunk(vacc, W1 + (size_t)rb * CHID * CHID, CHID, 0, CHID);

        __syncthreads();                        // all reads of relu(h) done
        #pragma unroll
        for (int j = 0; j < 32; ++j)
            A2[(jb + j) * LDAP + lane] = fmaxf(vacc[j], 0.f);
        __syncthreads();

        #pragma unroll
        for (int j = 0; j < 32; ++j) hacc[j] += b2[rb * CHID + jb + j];
        gemm_chunk(hacc, W2 + (size_t)rb * CHID * CHID, CHID, 0, CHID);
    }

    // ---- head: 7 dots per token from relu(h); waves split the outputs ----
    __syncthreads();
    #pragma unroll
    for (int j = 0; j < 32; ++j)
        A2[(jb + j) * LDAP + lane] = fmaxf(hacc[j], 0.f);
    __syncthreads();

    auto head_dot = [&](const float* __restrict__ wrow, float bias) {
        float dv = bias;
        #pragma unroll 1
        for (int r = 0; r < CHID; r += 8) {
            #pragma unroll
            for (int i = 0; i < 8; ++i)
                dv = fmaf(wrow[r + i], A2[(r + i) * LDAP + lane], dv);
        }
        return dv;
    };

    if (wv == 0) {
        const float c0 = head_dot(W_out, b_out[0]);
        const float av = head_dot(W_mult, b_mult[0]);
        const float bm = head_dot(W_mult + CHID, b_mult[1]);
        ws[g] = softplus_f(c0) * softplus_f(av) + softplus_f(bm);   // diag (unscaled)
    } else if (wv == 1) {
        ws[NTOK + g]     = head_dot(W_out + CHID, b_out[1]);
        ws[3 * NTOK + g] = head_dot(W_out + 3 * CHID, b_out[3]);
    } else if (wv == 2) {
        ws[2 * NTOK + g] = head_dot(W_out + 2 * CHID, b_out[2]);
        ws[4 * NTOK + g] = head_dot(W_out + 4 * CHID, b_out[4]);
    }
}

// Writes the three diagonals on top of the zeroed output.
__global__ __launch_bounds__(256) void band_kernel(
    const float* __restrict__ ws, const float* __restrict__ p_sm,
    float* __restrict__ out)
{
    const int g = (int)blockIdx.x * 256 + (int)threadIdx.x;   // 0..16383
    const int b = g >> 12;
    const int i = g & (N_SEQ - 1);
    const float sm = *p_sm;
    const float* v0 = ws;
    const float* c1 = ws + NTOK;
    const float* c2 = ws + 2 * NTOK;
    const float* c3 = ws + 3 * NTOK;
    const float* c4 = ws + 4 * NTOK;
    const size_t rowbase = (size_t)b * N_SEQ * N_SEQ + (size_t)i * N_SEQ;
    out[rowbase + i] = sm * v0[g];
    if (i >= 1) out[rowbase + i - 1] = sm * (c1[g] + c3[g - 1]);
    if (i >= 2) out[rowbase + i - 2] = sm * (c2[g] + c4[g - 2]);
}

extern "C" void kernel_launch(void* const* d_in, const int* in_sizes, int n_in,
                              void* d_out, int out_size, void* d_ws, size_t ws_size,
                              hipStream_t stream)
{
    const float* s      = (const float*)d_in[0];
    const float* s_init = (const float*)d_in[1];
    const float* dssp   = (const float*)d_in[2];
    const float* W_in   = (const float*)d_in[3];
    const float* b_in   = (const float*)d_in[4];
    const float* W_init = (const float*)d_in[5];
    const float* b_initp= (const float*)d_in[6];
    const float* W_dssp = (const float*)d_in[7];
    const float* b_dsspp= (const float*)d_in[8];
    const float* W1     = (const float*)d_in[9];
    const float* b1     = (const float*)d_in[10];
    const float* W2     = (const float*)d_in[11];
    const float* b2     = (const float*)d_in[12];
    const float* W_out  = (const float*)d_in[13];
    const float* b_out  = (const float*)d_in[14];
    const float* W_mult = (const float*)d_in[15];
    const float* b_mult = (const float*)d_in[16];
    const float* sm     = (const float*)d_in[17];
    float* ws  = (float*)d_ws;
    float* out = (float*)d_out;

    mlp_zero_kernel<<<MLP_BLOCKS + ZERO_BLOCKS, 256, 0, stream>>>(
        s, s_init, dssp, W_in, b_in, W_init, b_initp, W_dssp, b_dsspp,
        W1, b1, W2, b2, W_out, b_out, W_mult, b_mult, ws, out);

    band_kernel<<<NTOK / 256, 256, 0, stream>>>(ws, sm, out);
}

// Round 3
// 645.147 us; speedup vs baseline: 1.8186x; 1.8186x over previous
//
#include <hip/hip_runtime.h>
#include <math.h>

typedef __bf16 bf16_t;
typedef bf16_t bf16x8 __attribute__((ext_vector_type(8)));
typedef float  floatx4 __attribute__((ext_vector_type(4)));

constexpr int N_SEQ = 4096, BSZ = 4, CIN = 384, CDSSP = 64, CHID = 128, NBLK = 4;
constexpr int NTOK = BSZ * N_SEQ;                       // 16384
constexpr int TOK_PER_WAVE  = 32;
constexpr int TOK_PER_BLOCK = 128;                      // 4 waves
constexpr int MLP_BLOCKS  = NTOK / TOK_PER_BLOCK;       // 128
constexpr int ZERO_BLOCKS = 2048;
constexpr size_t OUT_ELEMS = (size_t)BSZ * N_SEQ * N_SEQ;

// ---- d_ws layout: bf16 hi/lo weight planes, then fp32 band arrays ----
constexpr int SZ_IN   = CHID * CIN;     // 49152
constexpr int SZ_DSSP = CHID * CDSSP;   // 8192
constexpr int SZ_HID  = CHID * CHID;    // 16384
constexpr int WHI_IN   = 0;
constexpr int WLO_IN   = WHI_IN   + SZ_IN;
constexpr int WHI_INIT = WLO_IN   + SZ_IN;
constexpr int WLO_INIT = WHI_INIT + SZ_IN;
constexpr int WHI_DSSP = WLO_INIT + SZ_IN;
constexpr int WLO_DSSP = WHI_DSSP + SZ_DSSP;
constexpr int WHI_1    = WLO_DSSP + SZ_DSSP;
constexpr int WLO_1    = WHI_1 + NBLK * SZ_HID;
constexpr int WHI_2    = WLO_1 + NBLK * SZ_HID;
constexpr int WLO_2    = WHI_2 + NBLK * SZ_HID;
constexpr int WSB_END  = WLO_2 + NBLK * SZ_HID;         // 475136 bf16 = 950272 B
constexpr int BAND_OFF = WSB_END / 2;                   // float index into ws
constexpr int PREP_TOTAL = 2 * SZ_IN + SZ_DSSP + 2 * NBLK * SZ_HID;  // 237568

__device__ __forceinline__ float softplus_f(float x) {
    return fmaxf(x, 0.f) + log1pf(expf(-fabsf(x)));
}
__device__ __forceinline__ unsigned short bf16_bits(bf16_t h) {
    union { bf16_t b; unsigned short u; } c; c.b = h; return c.u;
}
__device__ __forceinline__ bf16_t bits_bf16(unsigned int u) {
    union { unsigned short u; bf16_t b; } c; c.u = (unsigned short)u; return c.b;
}
__device__ __forceinline__ floatx4 mfma16(bf16x8 a, bf16x8 b, floatx4 c) {
    return __builtin_amdgcn_mfma_f32_16x16x32_bf16(a, b, c, 0, 0, 0);
}

// ---- split every weight matrix into bf16 hi + lo planes (exact: w = hi + lo + O(2^-18)) ----
__global__ __launch_bounds__(256) void prep_weights(
    const float* __restrict__ Win, const float* __restrict__ Winit,
    const float* __restrict__ Wd,  const float* __restrict__ W1,
    const float* __restrict__ W2,  bf16_t* __restrict__ wsb)
{
    int i = (int)blockIdx.x * 256 + (int)threadIdx.x;
    const float* src; int rel, hi, lo;
    if      (i < SZ_IN)                { src = Win;   rel = i;                       hi = WHI_IN;   lo = WLO_IN; }
    else if (i < 2*SZ_IN)              { src = Winit; rel = i - SZ_IN;               hi = WHI_INIT; lo = WLO_INIT; }
    else if (i < 2*SZ_IN + SZ_DSSP)    { src = Wd;    rel = i - 2*SZ_IN;             hi = WHI_DSSP; lo = WLO_DSSP; }
    else if (i < 2*SZ_IN + SZ_DSSP + NBLK*SZ_HID)
                                       { src = W1;    rel = i - 2*SZ_IN - SZ_DSSP;   hi = WHI_1;    lo = WLO_1; }
    else                               { src = W2;    rel = i - 2*SZ_IN - SZ_DSSP - NBLK*SZ_HID; hi = WHI_2; lo = WLO_2; }
    float x = src[rel];
    bf16_t h = (bf16_t)x;
    bf16_t l = (bf16_t)(x - (float)h);
    wsb[hi + rel] = h;
    wsb[lo + rel] = l;
}

// Fused: blocks [0,128) = MFMA MLP (matrix pipe); blocks [128,2176) = zero-fill (store pipe).
__global__ __launch_bounds__(256, 2) void mlp_zero_kernel(
    const float* __restrict__ s, const float* __restrict__ s_init,
    const float* __restrict__ dssp,
    const float* __restrict__ b_in, const float* __restrict__ b_init,
    const float* __restrict__ b_dssp,
    const float* __restrict__ b1, const float* __restrict__ b2,
    const float* __restrict__ W_out, const float* __restrict__ b_out,
    const float* __restrict__ W_mult, const float* __restrict__ b_mult,
    const bf16_t* __restrict__ wsb, float* __restrict__ band,
    float* __restrict__ out)
{
    // per-wave packed activation plane: Act[token][ch] = hi | lo<<16, pad 132 (4-bank rotate)
    __shared__ uint32_t Act[4][32][132];   // 67.6 KB

    if (blockIdx.x >= MLP_BLOCKS) {
        const int zb = (int)blockIdx.x - MLP_BLOCKS;
        const size_t chunk = OUT_ELEMS / ZERO_BLOCKS;      // 32768 floats
        float4* dst = (float4*)(out + (size_t)zb * chunk);
        const float4 z = make_float4(0.f, 0.f, 0.f, 0.f);
        for (int i = threadIdx.x; i < (int)(chunk / 4); i += 256) dst[i] = z;
        return;
    }

    const int tid  = (int)threadIdx.x;
    const int lane = tid & 63;
    const int wv   = tid >> 6;
    const int col  = lane & 15;    // MFMA: A-row (token), B-col (channel), C-col
    const int q    = lane >> 4;    // quad: k-offset group / C-row group
    const int t0w  = (int)blockIdx.x * TOK_PER_BLOCK + wv * TOK_PER_WAVE;
    uint32_t (*A)[132] = Act[wv];

    // h accumulators in C-frag layout: hacc[mt][nt] -> token mt*16 + q*4+r, ch nt*16+col
    floatx4 hacc[2][8];
    #pragma unroll
    for (int nt = 0; nt < 8; ++nt) {
        const int j = nt * 16 + col;
        const float b = b_in[j] + b_init[j] + b_dssp[j];
        floatx4 v = { b, b, b, b };
        hacc[0][nt] = v; hacc[1][nt] = v;
    }

    // ---- input layer: A-frags straight from global fp32 (relu + hi/lo split in VALU) ----
    auto input_pass = [&](const float* __restrict__ src, int C,
                          const bf16_t* __restrict__ whiP, const bf16_t* __restrict__ wloP) {
        for (int k0 = 0; k0 < C; k0 += 32) {
            bf16x8 ahi[2], alo[2];
            #pragma unroll
            for (int mt = 0; mt < 2; ++mt) {
                const float* p = src + (size_t)(t0w + mt * 16 + col) * C + k0 + q * 8;
                float4 x0 = *(const float4*)p;
                float4 x1 = *(const float4*)(p + 4);
                float xs[8] = { x0.x, x0.y, x0.z, x0.w, x1.x, x1.y, x1.z, x1.w };
                #pragma unroll
                for (int i = 0; i < 8; ++i) {
                    float r = fmaxf(xs[i], 0.f);
                    bf16_t h = (bf16_t)r;
                    ahi[mt][i] = h;
                    alo[mt][i] = (bf16_t)(r - (float)h);
                }
            }
            #pragma unroll 4
            for (int nt = 0; nt < 8; ++nt) {
                const size_t roff = (size_t)(nt * 16 + col) * C + k0 + q * 8;
                bf16x8 bhi = *(const bf16x8*)(whiP + roff);
                bf16x8 blo = *(const bf16x8*)(wloP + roff);
                #pragma unroll
                for (int mt = 0; mt < 2; ++mt) {
                    hacc[mt][nt] = mfma16(ahi[mt], bhi, hacc[mt][nt]);
                    hacc[mt][nt] = mfma16(alo[mt], bhi, hacc[mt][nt]);
                    hacc[mt][nt] = mfma16(ahi[mt], blo, hacc[mt][nt]);
                }
            }
        }
    };
    input_pass(s,      CIN,   wsb + WHI_IN,   wsb + WLO_IN);
    input_pass(s_init, CIN,   wsb + WHI_INIT, wsb + WLO_INIT);
    input_pass(dssp,   CDSSP, wsb + WHI_DSSP, wsb + WLO_DSSP);

    // ---- C-layout -> packed relu act plane (wave-private; no barrier needed) ----
    auto exchange = [&](floatx4 (&ac)[2][8]) {
        #pragma unroll
        for (int mt = 0; mt < 2; ++mt)
        #pragma unroll
        for (int nt = 0; nt < 8; ++nt)
        #pragma unroll
        for (int r = 0; r < 4; ++r) {
            float x = fmaxf(ac[mt][nt][r], 0.f);
            bf16_t h = (bf16_t)x;
            bf16_t l = (bf16_t)(x - (float)h);
            A[mt * 16 + q * 4 + r][nt * 16 + col] =
                (uint32_t)bf16_bits(h) | ((uint32_t)bf16_bits(l) << 16);
        }
    };

    // ---- hidden matmul from act plane (K = 128) ----
    auto hidden_pass = [&](floatx4 (&ac)[2][8],
                           const bf16_t* __restrict__ whiP, const bf16_t* __restrict__ wloP) {
        #pragma unroll
        for (int kg = 0; kg < 4; ++kg) {
            const int k0 = kg * 32;
            bf16x8 ahi[2], alo[2];
            #pragma unroll
            for (int mt = 0; mt < 2; ++mt) {
                const uint32_t* p = &A[mt * 16 + col][k0 + q * 8];
                uint4 u0 = *(const uint4*)p;
                uint4 u1 = *(const uint4*)(p + 4);
                uint32_t uu[8] = { u0.x, u0.y, u0.z, u0.w, u1.x, u1.y, u1.z, u1.w };
                union { uint32_t u[4]; bf16x8 v; } ch, cl;
                #pragma unroll
                for (int i = 0; i < 4; ++i) {
                    ch.u[i] = (uu[2*i] & 0xffffu) | (uu[2*i+1] << 16);
                    cl.u[i] = (uu[2*i] >> 16) | (uu[2*i+1] & 0xffff0000u);
                }
                ahi[mt] = ch.v; alo[mt] = cl.v;
            }
            #pragma unroll 4
            for (int nt = 0; nt < 8; ++nt) {
                const size_t roff = (size_t)(nt * 16 + col) * CHID + k0 + q * 8;
                bf16x8 bhi = *(const bf16x8*)(whiP + roff);
                bf16x8 blo = *(const bf16x8*)(wloP + roff);
                #pragma unroll
                for (int mt = 0; mt < 2; ++mt) {
                    ac[mt][nt] = mfma16(ahi[mt], bhi, ac[mt][nt]);
                    ac[mt][nt] = mfma16(alo[mt], bhi, ac[mt][nt]);
                    ac[mt][nt] = mfma16(ahi[mt], blo, ac[mt][nt]);
                }
            }
        }
    };

    // ---- resnet blocks ----
    #pragma unroll 1
    for (int rb = 0; rb < NBLK; ++rb) {
        exchange(hacc);                          // A = relu(h)
        floatx4 vacc[2][8];
        #pragma unroll
        for (int nt = 0; nt < 8; ++nt) {
            const float b = b1[rb * CHID + nt * 16 + col];
            floatx4 v = { b, b, b, b };
            vacc[0][nt] = v; vacc[1][nt] = v;
        }
        hidden_pass(vacc, wsb + WHI_1 + rb * SZ_HID, wsb + WLO_1 + rb * SZ_HID);
        exchange(vacc);                          // A = relu(v)
        #pragma unroll
        for (int nt = 0; nt < 8; ++nt) {
            const float b = b2[rb * CHID + nt * 16 + col];
            #pragma unroll
            for (int mt = 0; mt < 2; ++mt) {
                floatx4 t = hacc[mt][nt];
                t[0] += b; t[1] += b; t[2] += b; t[3] += b;
                hacc[mt][nt] = t;
            }
        }
        hidden_pass(hacc, wsb + WHI_2 + rb * SZ_HID, wsb + WLO_2 + rb * SZ_HID);
    }
    exchange(hacc);                              // A = relu(h_final) for the head

    // ---- head: 7 fp32 dots/token; half0 lanes do o=0..3, half1 do o=4,5,6 ----
    const int t    = lane & 31;
    const int half = lane >> 5;
    float d0v, d1v, d2v, d3v;
    const float *w0, *w1, *w2, *w3;
    if (half == 0) {
        w0 = W_out;            w1 = W_out + CHID;   w2 = W_out + 2*CHID; w3 = W_out + 3*CHID;
        d0v = b_out[0]; d1v = b_out[1]; d2v = b_out[2]; d3v = b_out[3];
    } else {
        w0 = W_out + 4*CHID;   w1 = W_mult;         w2 = W_mult + CHID;  w3 = W_out;
        d0v = b_out[4]; d1v = b_mult[0]; d2v = b_mult[1]; d3v = 0.f;
    }
    #pragma unroll 4
    for (int k = 0; k < CHID; ++k) {
        const uint32_t pk = A[t][k];
        const float x = (float)bits_bf16(pk & 0xffffu) + (float)bits_bf16(pk >> 16);
        d0v = fmaf(x, w0[k], d0v);
        d1v = fmaf(x, w1[k], d1v);
        d2v = fmaf(x, w2[k], d2v);
        d3v = fmaf(x, w3[k], d3v);
    }
    const float av = __shfl(d1v, 32 + t);   // half1's W_mult[0] dot
    const float bv = __shfl(d2v, 32 + t);   // half1's W_mult[1] dot
    const int g = t0w + t;
    if (half == 0) {
        band[g]            = softplus_f(d0v) * softplus_f(av) + softplus_f(bv);
        band[NTOK + g]     = d1v;   // c1
        band[2*NTOK + g]   = d2v;   // c2
        band[3*NTOK + g]   = d3v;   // c3
    } else {
        band[4*NTOK + g]   = d0v;   // c4
    }
}

// Writes the three diagonals on top of the zeroed output.
__global__ __launch_bounds__(256) void band_kernel(
    const float* __restrict__ band, const float* __restrict__ p_sm,
    float* __restrict__ out)
{
    const int g = (int)blockIdx.x * 256 + (int)threadIdx.x;   // 0..16383
    const int b = g >> 12;
    const int i = g & (N_SEQ - 1);
    const float sm = *p_sm;
    const size_t rowbase = (size_t)b * N_SEQ * N_SEQ + (size_t)i * N_SEQ;
    out[rowbase + i] = sm * band[g];
    if (i >= 1) out[rowbase + i - 1] = sm * (band[NTOK + g] + band[3*NTOK + g - 1]);
    if (i >= 2) out[rowbase + i - 2] = sm * (band[2*NTOK + g] + band[4*NTOK + g - 2]);
}

extern "C" void kernel_launch(void* const* d_in, const int* in_sizes, int n_in,
                              void* d_out, int out_size, void* d_ws, size_t ws_size,
                              hipStream_t stream)
{
    const float* s      = (const float*)d_in[0];
    const float* s_init = (const float*)d_in[1];
    const float* dssp   = (const float*)d_in[2];
    const float* W_in   = (const float*)d_in[3];
    const float* b_in   = (const float*)d_in[4];
    const float* W_init = (const float*)d_in[5];
    const float* b_initp= (const float*)d_in[6];
    const float* W_dssp = (const float*)d_in[7];
    const float* b_dsspp= (const float*)d_in[8];
    const float* W1     = (const float*)d_in[9];
    const float* b1     = (const float*)d_in[10];
    const float* W2     = (const float*)d_in[11];
    const float* b2     = (const float*)d_in[12];
    const float* W_out  = (const float*)d_in[13];
    const float* b_out  = (const float*)d_in[14];
    const float* W_mult = (const float*)d_in[15];
    const float* b_mult = (const float*)d_in[16];
    const float* sm     = (const float*)d_in[17];
    bf16_t* wsb = (bf16_t*)d_ws;
    float*  wsf = (float*)d_ws;
    float*  out = (float*)d_out;

    prep_weights<<<PREP_TOTAL / 256, 256, 0, stream>>>(W_in, W_init, W_dssp, W1, W2, wsb);

    mlp_zero_kernel<<<MLP_BLOCKS + ZERO_BLOCKS, 256, 0, stream>>>(
        s, s_init, dssp, b_in, b_initp, b_dsspp, b1, b2,
        W_out, b_out, W_mult, b_mult, (const bf16_t*)wsb, wsf + BAND_OFF, out);

    band_kernel<<<NTOK / 256, 256, 0, stream>>>(wsf + BAND_OFF, sm, out);
}

// Round 5
// 602.733 us; speedup vs baseline: 1.9466x; 1.0704x over previous
//
#include <hip/hip_runtime.h>
#include <math.h>

typedef __bf16 bf16_t;
typedef bf16_t bf16x8 __attribute__((ext_vector_type(8)));
typedef float  floatx4 __attribute__((ext_vector_type(4)));

constexpr int N_SEQ = 4096, BSZ = 4, CIN = 384, CDSSP = 64, CHID = 128, NBLK = 4;
constexpr int NTOK = BSZ * N_SEQ;                       // 16384
constexpr int TOK_PER_WAVE  = 32;
constexpr int TOK_PER_BLOCK = 128;                      // 4 waves
constexpr int MLP_BLOCKS  = NTOK / TOK_PER_BLOCK;       // 128

// ---- wsb layout in 16-byte units (1 unit = 8 bf16). Per 128-k chunk:
// hi plane 2048 units || lo plane 2048 units. Within a plane, element
// (j, k8) lives at unit j*16 + (k8 ^ (j&15))  -> global_load_lds streams it
// contiguously AND ds_read_b128 of B-frags is 2-way-conflict-free (free).
constexpr int U_SIN   = 0;                 // W_in: 3 chunks * 4096 units
constexpr int U_SINIT = 12288;             // W_init: 3 chunks
constexpr int U_DSSP  = 24576;             // 2048 units (hi 1024 || lo 1024, rowu=8, mask=7)
constexpr int U_W1    = 26624;             // 4 * 4096
constexpr int U_W2    = 43008;             // 4 * 4096
constexpr int U_END   = 59392;             // 950272 B
constexpr int BAND_OFF = U_END * 4;        // float index into d_ws for band arrays

typedef __attribute__((address_space(3))) bf16_t       lds_bf16_t;
typedef __attribute__((address_space(1))) const bf16_t glb_bf16_t;

__device__ __forceinline__ float softplus_f(float x) {
    return fmaxf(x, 0.f) + log1pf(expf(-fabsf(x)));
}
__device__ __forceinline__ unsigned short bf16_bits(bf16_t h) {
    union { bf16_t b; unsigned short u; } c; c.b = h; return c.u;
}
__device__ __forceinline__ bf16_t bits_bf16(unsigned int u) {
    union { unsigned short u; bf16_t b; } c; c.u = (unsigned short)u; return c.b;
}
__device__ __forceinline__ floatx4 mfma16(bf16x8 a, bf16x8 b, floatx4 c) {
    return __builtin_amdgcn_mfma_f32_16x16x32_bf16(a, b, c, 0, 0, 0);
}

// ---- prep: split weights into bf16 hi/lo and write the swizzled staging image ----
__global__ __launch_bounds__(256) void prep_weights(
    const float* __restrict__ Win, const float* __restrict__ Winit,
    const float* __restrict__ Wd,  const float* __restrict__ W1,
    const float* __restrict__ W2,  bf16_t* __restrict__ wsb)
{
    const int t = (int)blockIdx.x * 256 + (int)threadIdx.x;   // 0..29695, one per hi/lo unit pair
    const float* src; int hi_unit, lo_unit;
    if (t < 6144) {                       // W_in
        const int c = t >> 11, u = t & 2047;
        const int j = u >> 4, sw = u & 15, k8 = sw ^ (j & 15);
        src = Win + (size_t)j * CIN + c * 128 + k8 * 8;
        hi_unit = U_SIN + c * 4096 + u; lo_unit = hi_unit + 2048;
    } else if (t < 12288) {               // W_init
        const int tt = t - 6144, c = tt >> 11, u = tt & 2047;
        const int j = u >> 4, sw = u & 15, k8 = sw ^ (j & 15);
        src = Winit + (size_t)j * CIN + c * 128 + k8 * 8;
        hi_unit = U_SINIT + c * 4096 + u; lo_unit = hi_unit + 2048;
    } else if (t < 13312) {               // W_dssp (rowu=8, mask=7)
        const int u = t - 12288;
        const int j = u >> 3, sw = u & 7, k8 = sw ^ (j & 7);
        src = Wd + (size_t)j * CDSSP + k8 * 8;
        hi_unit = U_DSSP + u; lo_unit = hi_unit + 1024;
    } else if (t < 21504) {               // W1
        const int tt = t - 13312, rb = tt >> 11, u = tt & 2047;
        const int j = u >> 4, sw = u & 15, k8 = sw ^ (j & 15);
        src = W1 + (size_t)rb * CHID * CHID + (size_t)j * CHID + k8 * 8;
        hi_unit = U_W1 + rb * 4096 + u; lo_unit = hi_unit + 2048;
    } else {                              // W2
        const int tt = t - 21504, rb = tt >> 11, u = tt & 2047;
        const int j = u >> 4, sw = u & 15, k8 = sw ^ (j & 15);
        src = W2 + (size_t)rb * CHID * CHID + (size_t)j * CHID + k8 * 8;
        hi_unit = U_W2 + rb * 4096 + u; lo_unit = hi_unit + 2048;
    }
    const float4 a = *(const float4*)src;
    const float4 b = *(const float4*)(src + 4);
    const float xs[8] = { a.x, a.y, a.z, a.w, b.x, b.y, b.z, b.w };
    bf16x8 vh, vl;
    #pragma unroll
    for (int i = 0; i < 8; ++i) {
        const float x = xs[i];
        const bf16_t h = (bf16_t)x;
        vh[i] = h; vl[i] = (bf16_t)(x - (float)h);
    }
    *(bf16x8*)(wsb + (size_t)hi_unit * 8) = vh;
    *(bf16x8*)(wsb + (size_t)lo_unit * 8) = vl;
}

// ---- MLP: 128 blocks, wave = 32 tokens x 128 ch, weights staged to LDS ----
__global__ __launch_bounds__(256, 1) void mlp_kernel(
    const float* __restrict__ s, const float* __restrict__ s_init,
    const float* __restrict__ dssp,
    const float* __restrict__ b_in, const float* __restrict__ b_init,
    const float* __restrict__ b_dssp,
    const float* __restrict__ b1, const float* __restrict__ b2,
    const float* __restrict__ W_out, const float* __restrict__ b_out,
    const float* __restrict__ W_mult, const float* __restrict__ b_mult,
    const bf16_t* __restrict__ wsb, float* __restrict__ band)
{
    __shared__ uint32_t Act[4][32][132];            // 67.6 KB, per-wave act planes
    __shared__ __align__(16) bf16_t Wst[4096 * 8];  // 64 KB, staged weight chunk (hi||lo)

    const int tid  = (int)threadIdx.x;
    const int lane = tid & 63;
    const int wv   = tid >> 6;
    const int wvU  = __builtin_amdgcn_readfirstlane(wv);
    const int col  = lane & 15;
    const int q    = lane >> 4;
    const int t0w  = (int)blockIdx.x * TOK_PER_BLOCK + wv * TOK_PER_WAVE;
    uint32_t (*A)[132] = Act[wv];

    // async global->LDS stage of n_units 16B-units starting at wsb unit_base
    auto stage = [&](int unit_base, int n_units) {
        const int per_wave = n_units >> 2;
        const bf16_t* g = wsb + ((size_t)(unit_base + wvU * per_wave)) * 8 + lane * 8;
        bf16_t* l = Wst + (size_t)(wvU * per_wave) * 8;
        for (int u = 0; u < per_wave; u += 64) {
            __builtin_amdgcn_global_load_lds((const glb_bf16_t*)(g + (size_t)u * 8),
                                             (lds_bf16_t*)(l + (size_t)u * 8), 16, 0, 0);
        }
    };
    // B-frag fetch from staged LDS: row j = nt*16+col, k8 = kg*4+q
    auto bfrag = [&](int nt, int kg, int shift, int mask, int lo_off, bf16x8& bhi, bf16x8& blo) {
        const int sw = (kg * 4 + q) ^ (col & mask);
        const int u = ((nt * 16 + col) << shift) + sw;
        bhi = *(const bf16x8*)&Wst[(size_t)u * 8];
        blo = *(const bf16x8*)&Wst[(size_t)(u + lo_off) * 8];
    };

    // h accumulators (C-frag layout): hacc[mt][nt] -> token mt*16+q*4+r, ch nt*16+col
    floatx4 hacc[2][8];
    #pragma unroll
    for (int nt = 0; nt < 8; ++nt) {
        const int j = nt * 16 + col;
        const float b = b_in[j] + b_init[j] + b_dssp[j];
        floatx4 v = { b, b, b, b };
        hacc[0][nt] = v; hacc[1][nt] = v;
    }

    // ---- input passes: A from global fp32, B from staged LDS ----
    auto input_chunk = [&](const float* __restrict__ src, int C, int kc,
                           int nkg, int shift, int mask, int lo_off) {
        for (int kg = 0; kg < nkg; ++kg) {
            const int k0 = kc + kg * 32;
            bf16x8 ahi[2], alo[2];
            #pragma unroll
            for (int mt = 0; mt < 2; ++mt) {
                const float* p = src + (size_t)(t0w + mt * 16 + col) * C + k0 + q * 8;
                float4 x0 = *(const float4*)p;
                float4 x1 = *(const float4*)(p + 4);
                float xs[8] = { x0.x, x0.y, x0.z, x0.w, x1.x, x1.y, x1.z, x1.w };
                #pragma unroll
                for (int i = 0; i < 8; ++i) {
                    float r = fmaxf(xs[i], 0.f);
                    bf16_t h = (bf16_t)r;
                    ahi[mt][i] = h;
                    alo[mt][i] = (bf16_t)(r - (float)h);
                }
            }
            #pragma unroll 4
            for (int nt = 0; nt < 8; ++nt) {
                bf16x8 bhi, blo;
                bfrag(nt, kg, shift, mask, lo_off, bhi, blo);
                #pragma unroll
                for (int mt = 0; mt < 2; ++mt) {
                    hacc[mt][nt] = mfma16(ahi[mt], bhi, hacc[mt][nt]);
                    hacc[mt][nt] = mfma16(alo[mt], bhi, hacc[mt][nt]);
                    hacc[mt][nt] = mfma16(ahi[mt], blo, hacc[mt][nt]);
                }
            }
        }
    };

    // s: 3 chunks
    for (int c = 0; c < 3; ++c) {
        __syncthreads(); stage(U_SIN + c * 4096, 4096); __syncthreads();
        input_chunk(s, CIN, c * 128, 4, 4, 15, 2048);
    }
    // s_init: 3 chunks
    for (int c = 0; c < 3; ++c) {
        __syncthreads(); stage(U_SINIT + c * 4096, 4096); __syncthreads();
        input_chunk(s_init, CIN, c * 128, 4, 4, 15, 2048);
    }
    // dssp: 1 half-chunk (rowu=8, mask=7)
    __syncthreads(); stage(U_DSSP, 2048); __syncthreads();
    input_chunk(dssp, CDSSP, 0, 2, 3, 7, 1024);

    // ---- C-layout -> packed relu act plane (wave-private; no barrier needed) ----
    auto exchange = [&](floatx4 (&ac)[2][8]) {
        #pragma unroll
        for (int mt = 0; mt < 2; ++mt)
        #pragma unroll
        for (int nt = 0; nt < 8; ++nt)
        #pragma unroll
        for (int r = 0; r < 4; ++r) {
            float x = fmaxf(ac[mt][nt][r], 0.f);
            bf16_t h = (bf16_t)x;
            bf16_t l = (bf16_t)(x - (float)h);
            A[mt * 16 + q * 4 + r][nt * 16 + col] =
                (uint32_t)bf16_bits(h) | ((uint32_t)bf16_bits(l) << 16);
        }
    };

    // ---- hidden matmul: A from act plane, B from staged LDS (K=128) ----
    auto hidden_pass = [&](floatx4 (&ac)[2][8]) {
        #pragma unroll
        for (int kg = 0; kg < 4; ++kg) {
            const int k0 = kg * 32;
            bf16x8 ahi[2], alo[2];
            #pragma unroll
            for (int mt = 0; mt < 2; ++mt) {
                const uint32_t* p = &A[mt * 16 + col][k0 + q * 8];
                uint4 u0 = *(const uint4*)p;
                uint4 u1 = *(const uint4*)(p + 4);
                uint32_t uu[8] = { u0.x, u0.y, u0.z, u0.w, u1.x, u1.y, u1.z, u1.w };
                union { uint32_t u[4]; bf16x8 v; } ch, cl;
                #pragma unroll
                for (int i = 0; i < 4; ++i) {
                    ch.u[i] = (uu[2*i] & 0xffffu) | (uu[2*i+1] << 16);
                    cl.u[i] = (uu[2*i] >> 16) | (uu[2*i+1] & 0xffff0000u);
                }
                ahi[mt] = ch.v; alo[mt] = cl.v;
            }
            #pragma unroll 4
            for (int nt = 0; nt < 8; ++nt) {
                bf16x8 bhi, blo;
                bfrag(nt, kg, 4, 15, 2048, bhi, blo);
                #pragma unroll
                for (int mt = 0; mt < 2; ++mt) {
                    ac[mt][nt] = mfma16(ahi[mt], bhi, ac[mt][nt]);
                    ac[mt][nt] = mfma16(alo[mt], bhi, ac[mt][nt]);
                    ac[mt][nt] = mfma16(ahi[mt], blo, ac[mt][nt]);
                }
            }
        }
    };

    // ---- resnet blocks ----
    #pragma unroll 1
    for (int rb = 0; rb < NBLK; ++rb) {
        exchange(hacc);                          // A = relu(h)
        __syncthreads(); stage(U_W1 + rb * 4096, 4096); __syncthreads();
        floatx4 vacc[2][8];
        #pragma unroll
        for (int nt = 0; nt < 8; ++nt) {
            const float b = b1[rb * CHID + nt * 16 + col];
            floatx4 v = { b, b, b, b };
            vacc[0][nt] = v; vacc[1][nt] = v;
        }
        hidden_pass(vacc);

        exchange(vacc);                          // A = relu(v)
        __syncthreads(); stage(U_W2 + rb * 4096, 4096); __syncthreads();
        #pragma unroll
        for (int nt = 0; nt < 8; ++nt) {
            const float b = b2[rb * CHID + nt * 16 + col];
            #pragma unroll
            for (int mt = 0; mt < 2; ++mt) {
                floatx4 tt = hacc[mt][nt];
                tt[0] += b; tt[1] += b; tt[2] += b; tt[3] += b;
                hacc[mt][nt] = tt;
            }
        }
        hidden_pass(hacc);
    }
    exchange(hacc);                              // A = relu(h_final) for the head

    // ---- head: 7 fp32 dots/token; half0 lanes do o=0..3, half1 do o=4,5,6 ----
    const int t    = lane & 31;
    const int half = lane >> 5;
    float d0v, d1v, d2v, d3v;
    const float *w0, *w1, *w2, *w3;
    if (half == 0) {
        w0 = W_out;            w1 = W_out + CHID;   w2 = W_out + 2*CHID; w3 = W_out + 3*CHID;
        d0v = b_out[0]; d1v = b_out[1]; d2v = b_out[2]; d3v = b_out[3];
    } else {
        w0 = W_out + 4*CHID;   w1 = W_mult;         w2 = W_mult + CHID;  w3 = W_out;
        d0v = b_out[4]; d1v = b_mult[0]; d2v = b_mult[1]; d3v = 0.f;
    }
    #pragma unroll 4
    for (int k = 0; k < CHID; ++k) {
        const uint32_t pk = A[t][k];
        const float x = (float)bits_bf16(pk & 0xffffu) + (float)bits_bf16(pk >> 16);
        d0v = fmaf(x, w0[k], d0v);
        d1v = fmaf(x, w1[k], d1v);
        d2v = fmaf(x, w2[k], d2v);
        d3v = fmaf(x, w3[k], d3v);
    }
    const float av = __shfl(d1v, 32 + t);
    const float bv = __shfl(d2v, 32 + t);
    const int g = t0w + t;
    if (half == 0) {
        band[g]            = softplus_f(d0v) * softplus_f(av) + softplus_f(bv);
        band[NTOK + g]     = d1v;   // c1
        band[2*NTOK + g]   = d2v;   // c2
        band[3*NTOK + g]   = d3v;   // c3
    } else {
        band[4*NTOK + g]   = d0v;   // c4
    }
}

// ---- fused zero + band: one streaming pass over all 256 MB, nontemporal ----
__global__ __launch_bounds__(256) void zero_band_kernel(
    const float* __restrict__ band, const float* __restrict__ p_sm,
    float* __restrict__ out)
{
    const int row = (int)blockIdx.x;         // 0..16383 == token g
    const int i = row & (N_SEQ - 1);
    floatx4* dst = (floatx4*)(out + (size_t)row * N_SEQ);
    const floatx4 z = { 0.f, 0.f, 0.f, 0.f };
    #pragma unroll
    for (int it = 0; it < 4; ++it) {
        const int idx = (int)threadIdx.x + it * 256;   // float4 index in row
        const int c = idx * 4;
        if (c <= i && c + 5 >= i) {
            const float sm = *p_sm;
            const float e0 = sm * band[row];
            const float e1 = (i >= 1) ? sm * (band[NTOK + row] + band[3*NTOK + row - 1]) : 0.f;
            const float e2 = (i >= 2) ? sm * (band[2*NTOK + row] + band[4*NTOK + row - 2]) : 0.f;
            const int d = i - c;                        // 0..5
            floatx4 vals;
            #pragma unroll
            for (int jj = 0; jj < 4; ++jj) {
                const int dd = d - jj;
                vals[jj] = (dd == 0) ? e0 : (dd == 1 ? e1 : (dd == 2 ? e2 : 0.f));
            }
            dst[idx] = vals;
        } else {
            __builtin_nontemporal_store(z, dst + idx);
        }
    }
}

extern "C" void kernel_launch(void* const* d_in, const int* in_sizes, int n_in,
                              void* d_out, int out_size, void* d_ws, size_t ws_size,
                              hipStream_t stream)
{
    const float* s      = (const float*)d_in[0];
    const float* s_init = (const float*)d_in[1];
    const float* dssp   = (const float*)d_in[2];
    const float* W_in   = (const float*)d_in[3];
    const float* b_in   = (const float*)d_in[4];
    const float* W_init = (const float*)d_in[5];
    const float* b_initp= (const float*)d_in[6];
    const float* W_dssp = (const float*)d_in[7];
    const float* b_dsspp= (const float*)d_in[8];
    const float* W1     = (const float*)d_in[9];
    const float* b1     = (const float*)d_in[10];
    const float* W2     = (const float*)d_in[11];
    const float* b2     = (const float*)d_in[12];
    const float* W_out  = (const float*)d_in[13];
    const float* b_out  = (const float*)d_in[14];
    const float* W_mult = (const float*)d_in[15];
    const float* b_mult = (const float*)d_in[16];
    const float* sm     = (const float*)d_in[17];
    bf16_t* wsb  = (bf16_t*)d_ws;
    float*  band = (float*)d_ws + BAND_OFF;
    float*  out  = (float*)d_out;

    prep_weights<<<116, 256, 0, stream>>>(W_in, W_init, W_dssp, W1, W2, wsb);

    mlp_kernel<<<MLP_BLOCKS, 256, 0, stream>>>(
        s, s_init, dssp, b_in, b_initp, b_dsspp, b1, b2,
        W_out, b_out, W_mult, b_mult, (const bf16_t*)wsb, band);

    zero_band_kernel<<<NTOK, 256, 0, stream>>>(band, sm, out);
}

// Round 6
// 441.583 us; speedup vs baseline: 2.6570x; 1.3649x over previous
//
#include <hip/hip_runtime.h>
#include <math.h>

typedef __bf16 bf16_t;
typedef bf16_t bf16x8 __attribute__((ext_vector_type(8)));
typedef float  floatx4 __attribute__((ext_vector_type(4)));

constexpr int N_SEQ = 4096, BSZ = 4, CIN = 384, CDSSP = 64, CHID = 128, NBLK = 4;
constexpr int NTOK = BSZ * N_SEQ;                       // 16384
constexpr int TOK_PER_WAVE  = 32;
constexpr int MLP_BLOCKS  = NTOK / TOK_PER_WAVE;        // 512 single-wave blocks

// ---- wsb layout in 16-byte units (1 unit = 8 bf16), per matrix:
// hi plane (128*K8 units) || lo plane. Within a plane, element (j, k8) with
// nt=j>>4, col=j&15, kg=k8>>2, q=k8&3 lives at unit  nt*(16*K8) + kg*64 + col*4 + q.
// -> a wave's B-frag load for (nt,kg) is 64 lanes x 16 B CONTIGUOUS (1 KB).
constexpr int U_SIN   = 0;                 // W_in:   plane 6144 u, total 12288
constexpr int U_SINIT = 12288;             // W_init: total 12288
constexpr int U_DSSP  = 24576;             // W_dssp: plane 1024 u, total 2048
constexpr int U_W1    = 26624;             // 4 * (plane 2048 || lo 2048) = 16384
constexpr int U_W2    = 43008;             // 4 * 4096
constexpr int U_END   = 59392;             // 950272 B
constexpr int BAND_OFF = U_END * 4;        // float index into d_ws for band arrays

__device__ __forceinline__ float softplus_f(float x) {
    return fmaxf(x, 0.f) + log1pf(expf(-fabsf(x)));
}
__device__ __forceinline__ unsigned short bf16_bits(bf16_t h) {
    union { bf16_t b; unsigned short u; } c; c.b = h; return c.u;
}
__device__ __forceinline__ bf16_t bits_bf16(unsigned int u) {
    union { unsigned short u; bf16_t b; } c; c.u = (unsigned short)u; return c.b;
}
__device__ __forceinline__ floatx4 mfma16(bf16x8 a, bf16x8 b, floatx4 c) {
    return __builtin_amdgcn_mfma_f32_16x16x32_bf16(a, b, c, 0, 0, 0);
}

// ---- prep: split weights into bf16 hi/lo, write coalesced-B-frag image ----
__global__ __launch_bounds__(256) void prep_weights(
    const float* __restrict__ Win, const float* __restrict__ Winit,
    const float* __restrict__ Wd,  const float* __restrict__ W1,
    const float* __restrict__ W2,  bf16_t* __restrict__ wsb)
{
    const int t = (int)blockIdx.x * 256 + (int)threadIdx.x;   // 0..29695
    const float* src; int K, hi_base, plane, u;
    if (t < 6144)       { src = Win;   K = CIN;   hi_base = U_SIN;   plane = 6144; u = t; }
    else if (t < 12288) { src = Winit; K = CIN;   hi_base = U_SINIT; plane = 6144; u = t - 6144; }
    else if (t < 13312) { src = Wd;    K = CDSSP; hi_base = U_DSSP;  plane = 1024; u = t - 12288; }
    else if (t < 21504) { const int tt = t - 13312, rb = tt >> 11; u = tt & 2047;
                          src = W1 + (size_t)rb * CHID * CHID; K = CHID;
                          hi_base = U_W1 + rb * 4096; plane = 2048; }
    else                { const int tt = t - 21504, rb = tt >> 11; u = tt & 2047;
                          src = W2 + (size_t)rb * CHID * CHID; K = CHID;
                          hi_base = U_W2 + rb * 4096; plane = 2048; }
    const int K8 = K >> 3;
    const int nt = u / (16 * K8);
    const int r  = u - nt * 16 * K8;
    const int kg = r >> 6, r2 = r & 63, c = r2 >> 2, qq = r2 & 3;
    const int j = nt * 16 + c, k8 = kg * 4 + qq;
    const float* sp = src + (size_t)j * K + k8 * 8;
    const float4 a = *(const float4*)sp;
    const float4 b = *(const float4*)(sp + 4);
    const float xs[8] = { a.x, a.y, a.z, a.w, b.x, b.y, b.z, b.w };
    bf16x8 vh, vl;
    #pragma unroll
    for (int i = 0; i < 8; ++i) {
        const float x = xs[i];
        const bf16_t h = (bf16_t)x;
        vh[i] = h; vl[i] = (bf16_t)(x - (float)h);
    }
    *(bf16x8*)(wsb + ((size_t)hi_base + u) * 8)         = vh;
    *(bf16x8*)(wsb + ((size_t)hi_base + plane + u) * 8) = vl;
}

// ---- B-frag register set: hi/lo for all 8 nt of one kg ----
struct BF { bf16x8 h[8]; bf16x8 l[8]; };

__device__ __forceinline__ void loadB(const bf16_t* __restrict__ plane, int K8,
                                      int kg, int col, int q, BF& B) {
    const bf16_t* base = plane + (size_t)(kg * 64 + col * 4 + q) * 8;
    const size_t lo  = (size_t)128 * K8 * 8;     // lo plane offset (elements)
    const size_t nts = (size_t)16 * K8 * 8;      // nt step (elements)
    #pragma unroll
    for (int nt = 0; nt < 8; ++nt) {
        B.h[nt] = *(const bf16x8*)(base + nt * nts);
        B.l[nt] = *(const bf16x8*)(base + nt * nts + lo);
    }
}

__device__ __forceinline__ void mfma_step(const bf16x8 (&ahi)[2], const bf16x8 (&alo)[2],
                                          const BF& B, floatx4 (&ac)[2][8]) {
    #pragma unroll
    for (int nt = 0; nt < 8; ++nt)
        #pragma unroll
        for (int mt = 0; mt < 2; ++mt) {
            ac[mt][nt] = mfma16(ahi[mt], B.h[nt], ac[mt][nt]);
            ac[mt][nt] = mfma16(alo[mt], B.h[nt], ac[mt][nt]);
            ac[mt][nt] = mfma16(ahi[mt], B.l[nt], ac[mt][nt]);
        }
}

__device__ __forceinline__ void packA(const float (&xs)[8], bf16x8& hi, bf16x8& lo) {
    #pragma unroll
    for (int i = 0; i < 8; ++i) {
        const float r = fmaxf(xs[i], 0.f);
        const bf16_t h = (bf16_t)r;
        hi[i] = h; lo[i] = (bf16_t)(r - (float)h);
    }
}

// input pass: A-frags from global fp32 rows, B-frags register-double-buffered
template<int C>
__device__ __forceinline__ void input_pass(const float* __restrict__ src,
    const bf16_t* __restrict__ plane, int t0w, int col, int q, floatx4 (&hacc)[2][8])
{
    constexpr int K8 = C / 8, NKG = K8 / 4;
    BF B[2];
    loadB(plane, K8, 0, col, q, B[0]);
    #pragma unroll
    for (int kg = 0; kg < NKG; ++kg) {
        if (kg + 1 < NKG) loadB(plane, K8, kg + 1, col, q, B[(kg + 1) & 1]);
        bf16x8 ahi[2], alo[2];
        #pragma unroll
        for (int mt = 0; mt < 2; ++mt) {
            const float* p = src + (size_t)(t0w + mt * 16 + col) * C + kg * 32 + q * 8;
            const float4 x0 = *(const float4*)p;
            const float4 x1 = *(const float4*)(p + 4);
            const float xs[8] = { x0.x, x0.y, x0.z, x0.w, x1.x, x1.y, x1.z, x1.w };
            packA(xs, ahi[mt], alo[mt]);
        }
        mfma_step(ahi, alo, B[kg & 1], hacc);
    }
}

// hidden pass: A-frags from the wave-private Act plane (packed hi|lo per k)
__device__ __forceinline__ void hidden_pass(const uint32_t (*A)[132],
    const bf16_t* __restrict__ plane, int col, int q, floatx4 (&ac)[2][8])
{
    BF B[2];
    loadB(plane, 16, 0, col, q, B[0]);
    #pragma unroll
    for (int kg = 0; kg < 4; ++kg) {
        if (kg < 3) loadB(plane, 16, kg + 1, col, q, B[(kg + 1) & 1]);
        bf16x8 ahi[2], alo[2];
        #pragma unroll
        for (int mt = 0; mt < 2; ++mt) {
            const uint32_t* p = &A[mt * 16 + col][kg * 32 + q * 8];
            const uint4 u0 = *(const uint4*)p;
            const uint4 u1 = *(const uint4*)(p + 4);
            const uint32_t uu[8] = { u0.x, u0.y, u0.z, u0.w, u1.x, u1.y, u1.z, u1.w };
            union { uint32_t u[4]; bf16x8 v; } ch, cl;
            #pragma unroll
            for (int i = 0; i < 4; ++i) {
                ch.u[i] = (uu[2*i] & 0xffffu) | (uu[2*i+1] << 16);
                cl.u[i] = (uu[2*i] >> 16) | (uu[2*i+1] & 0xffff0000u);
            }
            ahi[mt] = ch.v; alo[mt] = cl.v;
        }
        mfma_step(ahi, alo, B[kg & 1], ac);
    }
}

// ---- MLP: 512 single-wave blocks, 32 tokens each, barrier-free ----
__global__ __launch_bounds__(64, 1) void mlp_kernel(
    const float* __restrict__ s, const float* __restrict__ s_init,
    const float* __restrict__ dssp,
    const float* __restrict__ b_in, const float* __restrict__ b_init,
    const float* __restrict__ b_dssp,
    const float* __restrict__ b1, const float* __restrict__ b2,
    const float* __restrict__ W_out, const float* __restrict__ b_out,
    const float* __restrict__ W_mult, const float* __restrict__ b_mult,
    const bf16_t* __restrict__ wsb, float* __restrict__ band)
{
    __shared__ uint32_t A[32][132];                 // 16.9 KB, wave-private act plane

    const int lane = (int)threadIdx.x;              // 0..63
    const int col  = lane & 15;
    const int q    = lane >> 4;
    const int t0w  = (int)blockIdx.x * TOK_PER_WAVE;

    // h accumulators (C-frag layout): hacc[mt][nt] -> token mt*16+q*4+r, ch nt*16+col
    floatx4 hacc[2][8];
    #pragma unroll
    for (int nt = 0; nt < 8; ++nt) {
        const int j = nt * 16 + col;
        const float b = b_in[j] + b_init[j] + b_dssp[j];
        floatx4 v = { b, b, b, b };
        hacc[0][nt] = v; hacc[1][nt] = v;
    }

    input_pass<CIN>  (s,      wsb + (size_t)U_SIN   * 8, t0w, col, q, hacc);
    input_pass<CIN>  (s_init, wsb + (size_t)U_SINIT * 8, t0w, col, q, hacc);
    input_pass<CDSSP>(dssp,   wsb + (size_t)U_DSSP  * 8, t0w, col, q, hacc);

    // C-layout -> packed relu act plane
    auto exchange = [&](floatx4 (&ac)[2][8]) {
        #pragma unroll
        for (int mt = 0; mt < 2; ++mt)
        #pragma unroll
        for (int nt = 0; nt < 8; ++nt)
        #pragma unroll
        for (int r = 0; r < 4; ++r) {
            const float x = fmaxf(ac[mt][nt][r], 0.f);
            const bf16_t h = (bf16_t)x;
            const bf16_t l = (bf16_t)(x - (float)h);
            A[mt * 16 + q * 4 + r][nt * 16 + col] =
                (uint32_t)bf16_bits(h) | ((uint32_t)bf16_bits(l) << 16);
        }
        __syncthreads();   // 1-wave barrier: orders DS write->read, nearly free
    };

    #pragma unroll 1
    for (int rb = 0; rb < NBLK; ++rb) {
        exchange(hacc);                               // A = relu(h)
        floatx4 vacc[2][8];
        #pragma unroll
        for (int nt = 0; nt < 8; ++nt) {
            const float b = b1[rb * CHID + nt * 16 + col];
            floatx4 v = { b, b, b, b };
            vacc[0][nt] = v; vacc[1][nt] = v;
        }
        hidden_pass(A, wsb + ((size_t)U_W1 + rb * 4096) * 8, col, q, vacc);

        exchange(vacc);                               // A = relu(v)
        #pragma unroll
        for (int nt = 0; nt < 8; ++nt) {
            const float b = b2[rb * CHID + nt * 16 + col];
            #pragma unroll
            for (int mt = 0; mt < 2; ++mt) {
                floatx4 tt = hacc[mt][nt];
                tt[0] += b; tt[1] += b; tt[2] += b; tt[3] += b;
                hacc[mt][nt] = tt;
            }
        }
        hidden_pass(A, wsb + ((size_t)U_W2 + rb * 4096) * 8, col, q, hacc);
    }
    exchange(hacc);                                   // A = relu(h_final)

    // ---- head: 7 fp32 dots/token; lanes 0-31 do o=0..3, lanes 32-63 do o=4,5,6 ----
    const int t    = lane & 31;
    const int half = lane >> 5;
    float d0v, d1v, d2v, d3v;
    const float *w0, *w1, *w2, *w3;
    if (half == 0) {
        w0 = W_out;          w1 = W_out + CHID; w2 = W_out + 2*CHID; w3 = W_out + 3*CHID;
        d0v = b_out[0]; d1v = b_out[1]; d2v = b_out[2]; d3v = b_out[3];
    } else {
        w0 = W_out + 4*CHID; w1 = W_mult;       w2 = W_mult + CHID;  w3 = W_out;
        d0v = b_out[4]; d1v = b_mult[0]; d2v = b_mult[1]; d3v = 0.f;
    }
    #pragma unroll 4
    for (int k = 0; k < CHID; ++k) {
        const uint32_t pk = A[t][k];
        const float x = (float)bits_bf16(pk & 0xffffu) + (float)bits_bf16(pk >> 16);
        d0v = fmaf(x, w0[k], d0v);
        d1v = fmaf(x, w1[k], d1v);
        d2v = fmaf(x, w2[k], d2v);
        d3v = fmaf(x, w3[k], d3v);
    }
    const float av = __shfl(d1v, 32 + t);
    const float bv = __shfl(d2v, 32 + t);
    const int g = t0w + t;
    if (half == 0) {
        band[g]            = softplus_f(d0v) * softplus_f(av) + softplus_f(bv);
        band[NTOK + g]     = d1v;   // c1
        band[2*NTOK + g]   = d2v;   // c2
        band[3*NTOK + g]   = d3v;   // c3
    } else {
        band[4*NTOK + g]   = d0v;   // c4
    }
}

// ---- fused zero + band: one streaming pass over all 256 MB, nontemporal ----
__global__ __launch_bounds__(256) void zero_band_kernel(
    const float* __restrict__ band, const float* __restrict__ p_sm,
    float* __restrict__ out)
{
    const int row = (int)blockIdx.x;         // 0..16383 == token g
    const int i = row & (N_SEQ - 1);
    floatx4* dst = (floatx4*)(out + (size_t)row * N_SEQ);
    const floatx4 z = { 0.f, 0.f, 0.f, 0.f };
    #pragma unroll
    for (int it = 0; it < 4; ++it) {
        const int idx = (int)threadIdx.x + it * 256;   // float4 index in row
        const int c = idx * 4;
        if (c <= i && c + 5 >= i) {
            const float sm = *p_sm;
            const float e0 = sm * band[row];
            const float e1 = (i >= 1) ? sm * (band[NTOK + row] + band[3*NTOK + row - 1]) : 0.f;
            const float e2 = (i >= 2) ? sm * (band[2*NTOK + row] + band[4*NTOK + row - 2]) : 0.f;
            const int d = i - c;                        // 0..5
            floatx4 vals;
            #pragma unroll
            for (int jj = 0; jj < 4; ++jj) {
                const int dd = d - jj;
                vals[jj] = (dd == 0) ? e0 : (dd == 1 ? e1 : (dd == 2 ? e2 : 0.f));
            }
            dst[idx] = vals;
        } else {
            __builtin_nontemporal_store(z, dst + idx);
        }
    }
}

extern "C" void kernel_launch(void* const* d_in, const int* in_sizes, int n_in,
                              void* d_out, int out_size, void* d_ws, size_t ws_size,
                              hipStream_t stream)
{
    const float* s      = (const float*)d_in[0];
    const float* s_init = (const float*)d_in[1];
    const float* dssp   = (const float*)d_in[2];
    const float* W_in   = (const float*)d_in[3];
    const float* b_in   = (const float*)d_in[4];
    const float* W_init = (const float*)d_in[5];
    const float* b_initp= (const float*)d_in[6];
    const float* W_dssp = (const float*)d_in[7];
    const float* b_dsspp= (const float*)d_in[8];
    const float* W1     = (const float*)d_in[9];
    const float* b1     = (const float*)d_in[10];
    const float* W2     = (const float*)d_in[11];
    const float* b2     = (const float*)d_in[12];
    const float* W_out  = (const float*)d_in[13];
    const float* b_out  = (const float*)d_in[14];
    const float* W_mult = (const float*)d_in[15];
    const float* b_mult = (const float*)d_in[16];
    const float* sm     = (const float*)d_in[17];
    bf16_t* wsb  = (bf16_t*)d_ws;
    float*  band = (float*)d_ws + BAND_OFF;
    float*  out  = (float*)d_out;

    prep_weights<<<116, 256, 0, stream>>>(W_in, W_init, W_dssp, W1, W2, wsb);

    mlp_kernel<<<MLP_BLOCKS, 64, 0, stream>>>(
        s, s_init, dssp, b_in, b_initp, b_dsspp, b1, b2,
        W_out, b_out, W_mult, b_mult, (const bf16_t*)wsb, band);

    zero_band_kernel<<<NTOK, 256, 0, stream>>>(band, sm, out);
}

// Round 7
// 402.998 us; speedup vs baseline: 2.9114x; 1.0957x over previous
//
#include <hip/hip_runtime.h>
#include <math.h>

typedef __bf16 bf16_t;
typedef bf16_t bf16x8 __attribute__((ext_vector_type(8)));
typedef float  floatx4 __attribute__((ext_vector_type(4)));

constexpr int N_SEQ = 4096, BSZ = 4, CIN = 384, CDSSP = 64, CHID = 128, NBLK = 4;
constexpr int NTOK = BSZ * N_SEQ;                       // 16384
constexpr int TOK_PER_WAVE  = 32;
constexpr int MLP_BLOCKS  = NTOK / TOK_PER_WAVE;        // 512 single-wave blocks

// ---- wsb layout in 16-byte units (1 unit = 8 bf16), per matrix:
// hi plane (128*K8 units) || lo plane. Within a plane, element (j, k8) with
// nt=j>>4, col=j&15, kg=k8>>2, q=k8&3 lives at unit  nt*(16*K8) + kg*64 + col*4 + q.
// -> a wave's B-frag load for (nt,kg) is 64 lanes x 16 B CONTIGUOUS (1 KB).
constexpr int U_SIN   = 0;                 // W_in:   plane 6144 u, total 12288
constexpr int U_SINIT = 12288;             // W_init: total 12288
constexpr int U_DSSP  = 24576;             // W_dssp: plane 1024 u, total 2048
constexpr int U_W1    = 26624;             // 4 * 4096
constexpr int U_W2    = 43008;             // 4 * 4096
constexpr int U_END   = 59392;             // 950272 B
constexpr int BAND_OFF = U_END * 4;        // float index into d_ws for band arrays

__device__ __forceinline__ float softplus_f(float x) {
    return fmaxf(x, 0.f) + log1pf(expf(-fabsf(x)));
}
__device__ __forceinline__ unsigned short bf16_bits(bf16_t h) {
    union { bf16_t b; unsigned short u; } c; c.b = h; return c.u;
}
__device__ __forceinline__ bf16_t bits_bf16(unsigned int u) {
    union { unsigned short u; bf16_t b; } c; c.u = (unsigned short)u; return c.b;
}
__device__ __forceinline__ floatx4 mfma16(bf16x8 a, bf16x8 b, floatx4 c) {
    return __builtin_amdgcn_mfma_f32_16x16x32_bf16(a, b, c, 0, 0, 0);
}

// ---- prep: split weights into bf16 hi/lo, write coalesced-B-frag image ----
__global__ __launch_bounds__(256) void prep_weights(
    const float* __restrict__ Win, const float* __restrict__ Winit,
    const float* __restrict__ Wd,  const float* __restrict__ W1,
    const float* __restrict__ W2,  bf16_t* __restrict__ wsb)
{
    const int t = (int)blockIdx.x * 256 + (int)threadIdx.x;   // 0..29695
    const float* src; int K, hi_base, plane, u;
    if (t < 6144)       { src = Win;   K = CIN;   hi_base = U_SIN;   plane = 6144; u = t; }
    else if (t < 12288) { src = Winit; K = CIN;   hi_base = U_SINIT; plane = 6144; u = t - 6144; }
    else if (t < 13312) { src = Wd;    K = CDSSP; hi_base = U_DSSP;  plane = 1024; u = t - 12288; }
    else if (t < 21504) { const int tt = t - 13312, rb = tt >> 11; u = tt & 2047;
                          src = W1 + (size_t)rb * CHID * CHID; K = CHID;
                          hi_base = U_W1 + rb * 4096; plane = 2048; }
    else                { const int tt = t - 21504, rb = tt >> 11; u = tt & 2047;
                          src = W2 + (size_t)rb * CHID * CHID; K = CHID;
                          hi_base = U_W2 + rb * 4096; plane = 2048; }
    const int K8 = K >> 3;
    const int nt = u / (16 * K8);
    const int r  = u - nt * 16 * K8;
    const int kg = r >> 6, r2 = r & 63, c = r2 >> 2, qq = r2 & 3;
    const int j = nt * 16 + c, k8 = kg * 4 + qq;
    const float* sp = src + (size_t)j * K + k8 * 8;
    const float4 a = *(const float4*)sp;
    const float4 b = *(const float4*)(sp + 4);
    const float xs[8] = { a.x, a.y, a.z, a.w, b.x, b.y, b.z, b.w };
    bf16x8 vh, vl;
    #pragma unroll
    for (int i = 0; i < 8; ++i) {
        const float x = xs[i];
        const bf16_t h = (bf16_t)x;
        vh[i] = h; vl[i] = (bf16_t)(x - (float)h);
    }
    *(bf16x8*)(wsb + ((size_t)hi_base + u) * 8)         = vh;
    *(bf16x8*)(wsb + ((size_t)hi_base + plane + u) * 8) = vl;
}

// ---- B-frag register set: hi/lo for all 8 nt of one kg ----
struct BF { bf16x8 h[8]; bf16x8 l[8]; };

__device__ __forceinline__ void loadB(const bf16_t* __restrict__ plane, int K8,
                                      int kg, int col, int q, BF& B) {
    const bf16_t* base = plane + (size_t)(kg * 64 + col * 4 + q) * 8;
    const size_t lo  = (size_t)128 * K8 * 8;     // lo plane offset (elements)
    const size_t nts = (size_t)16 * K8 * 8;      // nt step (elements)
    #pragma unroll
    for (int nt = 0; nt < 8; ++nt) {
        B.h[nt] = *(const bf16x8*)(base + nt * nts);
        B.l[nt] = *(const bf16x8*)(base + nt * nts + lo);
    }
}

__device__ __forceinline__ void mfma_step(const bf16x8 (&ahi)[2], const bf16x8 (&alo)[2],
                                          const BF& B, floatx4 (&ac)[2][8]) {
    #pragma unroll
    for (int nt = 0; nt < 8; ++nt)
        #pragma unroll
        for (int mt = 0; mt < 2; ++mt) {
            ac[mt][nt] = mfma16(ahi[mt], B.h[nt], ac[mt][nt]);
            ac[mt][nt] = mfma16(alo[mt], B.h[nt], ac[mt][nt]);
            ac[mt][nt] = mfma16(ahi[mt], B.l[nt], ac[mt][nt]);
        }
}

__device__ __forceinline__ void packXA(const float4 (&X)[2][2],
                                       bf16x8 (&ahi)[2], bf16x8 (&alo)[2]) {
    #pragma unroll
    for (int mt = 0; mt < 2; ++mt) {
        const float xs[8] = { X[mt][0].x, X[mt][0].y, X[mt][0].z, X[mt][0].w,
                              X[mt][1].x, X[mt][1].y, X[mt][1].z, X[mt][1].w };
        #pragma unroll
        for (int i = 0; i < 8; ++i) {
            const float r = fmaxf(xs[i], 0.f);
            const bf16_t h = (bf16_t)r;
            ahi[mt][i] = h;
            alo[mt][i] = (bf16_t)(r - (float)h);
        }
    }
}

// A-frags from the wave-private Act plane (packed hi|lo per k)
__device__ __forceinline__ void ldsA(const uint32_t (*A)[132], int kg, int col, int q,
                                     bf16x8 (&ahi)[2], bf16x8 (&alo)[2]) {
    #pragma unroll
    for (int mt = 0; mt < 2; ++mt) {
        const uint32_t* p = &A[mt * 16 + col][kg * 32 + q * 8];
        const uint4 u0 = *(const uint4*)p;
        const uint4 u1 = *(const uint4*)(p + 4);
        const uint32_t uu[8] = { u0.x, u0.y, u0.z, u0.w, u1.x, u1.y, u1.z, u1.w };
        union { uint32_t u[4]; bf16x8 v; } ch, cl;
        #pragma unroll
        for (int i = 0; i < 4; ++i) {
            ch.u[i] = (uu[2*i] & 0xffffu) | (uu[2*i+1] << 16);
            cl.u[i] = (uu[2*i] >> 16) | (uu[2*i+1] & 0xffff0000u);
        }
        ahi[mt] = ch.v; alo[mt] = cl.v;
    }
}

// hidden matmul (K=128), rolled kg loop, B double-buffered
__device__ __forceinline__ void hidden_pass(const uint32_t (*A)[132],
    const bf16_t* __restrict__ plane, int col, int q, floatx4 (&ac)[2][8])
{
    BF B[2];
    loadB(plane, 16, 0, col, q, B[0]);
    #pragma unroll 1
    for (int kg = 0; kg < 4; kg += 2) {
        loadB(plane, 16, kg + 1, col, q, B[1]);
        bf16x8 ahi[2], alo[2];
        ldsA(A, kg, col, q, ahi, alo);
        mfma_step(ahi, alo, B[0], ac);
        if (kg + 2 < 4) loadB(plane, 16, kg + 2, col, q, B[0]);
        ldsA(A, kg + 1, col, q, ahi, alo);
        mfma_step(ahi, alo, B[1], ac);
    }
}

// ---- MLP: 512 single-wave blocks, 32 tokens each, rolled loops (I$-friendly) ----
__global__ __launch_bounds__(64) void mlp_kernel(
    const float* __restrict__ s, const float* __restrict__ s_init,
    const float* __restrict__ dssp,
    const float* __restrict__ b_in, const float* __restrict__ b_init,
    const float* __restrict__ b_dssp,
    const float* __restrict__ b1, const float* __restrict__ b2,
    const float* __restrict__ W_out, const float* __restrict__ b_out,
    const float* __restrict__ W_mult, const float* __restrict__ b_mult,
    const bf16_t* __restrict__ wsb, float* __restrict__ band)
{
    __shared__ uint32_t A[32][132];                 // 16.9 KB, wave-private act plane

    const int lane = (int)threadIdx.x;              // 0..63
    const int col  = lane & 15;
    const int q    = lane >> 4;
    const int t0w  = (int)blockIdx.x * TOK_PER_WAVE;

    // h accumulators (C-frag layout): hacc[mt][nt] -> token mt*16+q*4+r, ch nt*16+col
    floatx4 hacc[2][8];
    #pragma unroll
    for (int nt = 0; nt < 8; ++nt) {
        const int j = nt * 16 + col;
        const float b = b_in[j] + b_init[j] + b_dssp[j];
        floatx4 v = { b, b, b, b };
        hacc[0][nt] = v; hacc[1][nt] = v;
    }

    auto loadA = [&](const float* __restrict__ src, int C, int kg, float4 (&X)[2][2]) {
        #pragma unroll
        for (int mt = 0; mt < 2; ++mt) {
            const float* p = src + (size_t)(t0w + mt * 16 + col) * C + kg * 32 + q * 8;
            X[mt][0] = *(const float4*)p;
            X[mt][1] = *(const float4*)(p + 4);
        }
    };

    // ---- input segments: one rolled, software-pipelined kg loop ----
    #pragma unroll 1
    for (int seg = 0; seg < 3; ++seg) {
        const float* src = (seg == 0) ? s : (seg == 1) ? s_init : dssp;
        const int C   = (seg == 2) ? CDSSP : CIN;
        const int NKG = C >> 5;
        const int K8  = C >> 3;
        const bf16_t* plane = wsb +
            (size_t)((seg == 0) ? U_SIN : (seg == 1) ? U_SINIT : U_DSSP) * 8;

        float4 XA[2][2][2];
        BF B[2];
        loadA(src, C, 0, XA[0]);
        loadB(plane, K8, 0, col, q, B[0]);
        #pragma unroll 1
        for (int kg = 0; kg < NKG; kg += 2) {
            if (kg + 1 < NKG) { loadA(src, C, kg + 1, XA[1]); loadB(plane, K8, kg + 1, col, q, B[1]); }
            bf16x8 ahi[2], alo[2];
            packXA(XA[0], ahi, alo);
            mfma_step(ahi, alo, B[0], hacc);
            if (kg + 2 < NKG) { loadA(src, C, kg + 2, XA[0]); loadB(plane, K8, kg + 2, col, q, B[0]); }
            if (kg + 1 < NKG) {
                packXA(XA[1], ahi, alo);
                mfma_step(ahi, alo, B[1], hacc);
            }
        }
    }

    // C-layout -> packed relu act plane
    auto exchange = [&](floatx4 (&ac)[2][8]) {
        #pragma unroll
        for (int mt = 0; mt < 2; ++mt)
        #pragma unroll
        for (int nt = 0; nt < 8; ++nt)
        #pragma unroll
        for (int r = 0; r < 4; ++r) {
            const float x = fmaxf(ac[mt][nt][r], 0.f);
            const bf16_t h = (bf16_t)x;
            const bf16_t l = (bf16_t)(x - (float)h);
            A[mt * 16 + q * 4 + r][nt * 16 + col] =
                (uint32_t)bf16_bits(h) | ((uint32_t)bf16_bits(l) << 16);
        }
        __syncthreads();   // 1-wave barrier: orders DS write->read, nearly free
    };

    #pragma unroll 1
    for (int rb = 0; rb < NBLK; ++rb) {
        exchange(hacc);                               // A = relu(h)
        floatx4 vacc[2][8];
        #pragma unroll
        for (int nt = 0; nt < 8; ++nt) {
            const float b = b1[rb * CHID + nt * 16 + col];
            floatx4 v = { b, b, b, b };
            vacc[0][nt] = v; vacc[1][nt] = v;
        }
        hidden_pass(A, wsb + ((size_t)U_W1 + rb * 4096) * 8, col, q, vacc);

        exchange(vacc);                               // A = relu(v)
        #pragma unroll
        for (int nt = 0; nt < 8; ++nt) {
            const float b = b2[rb * CHID + nt * 16 + col];
            #pragma unroll
            for (int mt = 0; mt < 2; ++mt) {
                floatx4 tt = hacc[mt][nt];
                tt[0] += b; tt[1] += b; tt[2] += b; tt[3] += b;
                hacc[mt][nt] = tt;
            }
        }
        hidden_pass(A, wsb + ((size_t)U_W2 + rb * 4096) * 8, col, q, hacc);
    }
    exchange(hacc);                                   // A = relu(h_final)

    // ---- head: 7 fp32 dots/token; lanes 0-31 do o=0..3, lanes 32-63 do o=4,5,6 ----
    const int t    = lane & 31;
    const int half = lane >> 5;
    float d0v, d1v, d2v, d3v;
    const float *w0, *w1, *w2, *w3;
    if (half == 0) {
        w0 = W_out;          w1 = W_out + CHID; w2 = W_out + 2*CHID; w3 = W_out + 3*CHID;
        d0v = b_out[0]; d1v = b_out[1]; d2v = b_out[2]; d3v = b_out[3];
    } else {
        w0 = W_out + 4*CHID; w1 = W_mult;       w2 = W_mult + CHID;  w3 = W_out;
        d0v = b_out[4]; d1v = b_mult[0]; d2v = b_mult[1]; d3v = 0.f;
    }
    #pragma unroll 1
    for (int k = 0; k < CHID; ++k) {
        const uint32_t pk = A[t][k];
        const float x = (float)bits_bf16(pk & 0xffffu) + (float)bits_bf16(pk >> 16);
        d0v = fmaf(x, w0[k], d0v);
        d1v = fmaf(x, w1[k], d1v);
        d2v = fmaf(x, w2[k], d2v);
        d3v = fmaf(x, w3[k], d3v);
    }
    const float av = __shfl(d1v, 32 + t);
    const float bv = __shfl(d2v, 32 + t);
    const int g = t0w + t;
    if (half == 0) {
        band[g]            = softplus_f(d0v) * softplus_f(av) + softplus_f(bv);
        band[NTOK + g]     = d1v;   // c1
        band[2*NTOK + g]   = d2v;   // c2
        band[3*NTOK + g]   = d3v;   // c3
    } else {
        band[4*NTOK + g]   = d0v;   // c4
    }
}

// ---- pure streaming zero-fill: branch-free nontemporal stores ----
__global__ __launch_bounds__(256) void zero_fill(float* __restrict__ out)
{
    floatx4* dst = (floatx4*)(out + (size_t)blockIdx.x * 32768);   // 128 KB/block
    const floatx4 z = { 0.f, 0.f, 0.f, 0.f };
    #pragma unroll 1
    for (int i = (int)threadIdx.x; i < 8192; i += 256)
        __builtin_nontemporal_store(z, dst + i);
}

// ---- patch the three diagonals (each cell fully overwritten; no RMW) ----
__global__ __launch_bounds__(256) void band_patch(
    const float* __restrict__ band, const float* __restrict__ p_sm,
    float* __restrict__ out)
{
    const int g = (int)blockIdx.x * 256 + (int)threadIdx.x;   // 0..16383
    const int b = g >> 12;
    const int i = g & (N_SEQ - 1);
    const float sm = *p_sm;
    const size_t rowbase = (size_t)b * N_SEQ * N_SEQ + (size_t)i * N_SEQ;
    out[rowbase + i] = sm * band[g];
    if (i >= 1) out[rowbase + i - 1] = sm * (band[NTOK + g] + band[3*NTOK + g - 1]);
    if (i >= 2) out[rowbase + i - 2] = sm * (band[2*NTOK + g] + band[4*NTOK + g - 2]);
}

extern "C" void kernel_launch(void* const* d_in, const int* in_sizes, int n_in,
                              void* d_out, int out_size, void* d_ws, size_t ws_size,
                              hipStream_t stream)
{
    const float* s      = (const float*)d_in[0];
    const float* s_init = (const float*)d_in[1];
    const float* dssp   = (const float*)d_in[2];
    const float* W_in   = (const float*)d_in[3];
    const float* b_in   = (const float*)d_in[4];
    const float* W_init = (const float*)d_in[5];
    const float* b_initp= (const float*)d_in[6];
    const float* W_dssp = (const float*)d_in[7];
    const float* b_dsspp= (const float*)d_in[8];
    const float* W1     = (const float*)d_in[9];
    const float* b1     = (const float*)d_in[10];
    const float* W2     = (const float*)d_in[11];
    const float* b2     = (const float*)d_in[12];
    const float* W_out  = (const float*)d_in[13];
    const float* b_out  = (const float*)d_in[14];
    const float* W_mult = (const float*)d_in[15];
    const float* b_mult = (const float*)d_in[16];
    const float* sm     = (const float*)d_in[17];
    bf16_t* wsb  = (bf16_t*)d_ws;
    float*  band = (float*)d_ws + BAND_OFF;
    float*  out  = (float*)d_out;

    prep_weights<<<116, 256, 0, stream>>>(W_in, W_init, W_dssp, W1, W2, wsb);

    mlp_kernel<<<MLP_BLOCKS, 64, 0, stream>>>(
        s, s_init, dssp, b_in, b_initp, b_dsspp, b1, b2,
        W_out, b_out, W_mult, b_mult, (const bf16_t*)wsb, band);

    zero_fill<<<2048, 256, 0, stream>>>(out);

    band_patch<<<NTOK / 256, 256, 0, stream>>>(band, sm, out);
}